// Round 4
// baseline (807.660 us; speedup 1.0000x reference)
//
#include <hip/hip_runtime.h>
#include <stdint.h>

#define NT 500000
#define NC 100000
#define NM 20000
#define NE 500000

#define CBLK 6250   // client blocks in agg_proj (16 nodes each -> 100,000)
#define MBLK 1250   // merchant blocks (16 each -> 20,000)

// ---------- small dense precompute: Weq = W1 @ Wf, beq = b1 @ Wf ----------
__global__ __launch_bounds__(256) void weq_kernel(const float* __restrict__ W1c,
                                                  const float* __restrict__ b1c,
                                                  const float* __restrict__ W1m,
                                                  const float* __restrict__ b1m,
                                                  const float* __restrict__ Wf,
                                                  float* __restrict__ WeqC,
                                                  float* __restrict__ WeqM,
                                                  float* __restrict__ beq) {
    int t = threadIdx.x;
    if (t < 128) {
        int k = t >> 1, o = t & 1;
        float s = 0.0f;
        for (int j = 0; j < 64; j++) s += W1c[k * 64 + j] * Wf[j * 2 + o];
        WeqC[k * 2 + o] = s;
    } else {
        int k = (t - 128) >> 1, o = t & 1;
        float s = 0.0f;
        for (int j = 0; j < 64; j++) s += W1m[k * 64 + j] * Wf[j * 2 + o];
        WeqM[k * 2 + o] = s;
    }
    if (t < 4) {
        const float* b = (t < 2) ? b1c : b1m;
        int o = t & 1;
        float s = 0.0f;
        for (int j = 0; j < 64; j++) s += b[j] * Wf[j * 2 + o];
        beq[t] = s;
    }
}

// ---------- linked-chain build: ALL FOUR relations in one launch ----------
__global__ __launch_bounds__(256) void chain4(const int* __restrict__ sTC,
                                              const int* __restrict__ dTC,
                                              const int* __restrict__ sTM,
                                              const int* __restrict__ dTM,
                                              const int* __restrict__ sCT,
                                              const int* __restrict__ dCT,
                                              const int* __restrict__ sMT,
                                              const int* __restrict__ dMT,
                                              int* __restrict__ headC,
                                              int* __restrict__ headM,
                                              int* __restrict__ headTC,
                                              int* __restrict__ headTM,
                                              int2* __restrict__ recC,
                                              int2* __restrict__ recM,
                                              int2* __restrict__ recTC,
                                              int2* __restrict__ recTM) {
    int id = blockIdx.x * 256 + threadIdx.x;
    int r = id / NE;
    if (r > 3) return;
    int e = id - r * NE;
    const int* src; const int* dst; int* head; int2* rec;
    if (r == 0)      { src = sTC; dst = dTC; head = headC;  rec = recC; }
    else if (r == 1) { src = sTM; dst = dTM; head = headM;  rec = recM; }
    else if (r == 2) { src = sCT; dst = dCT; head = headTC; rec = recTC; }
    else             { src = sMT; dst = dMT; head = headTM; rec = recTM; }
    int d = dst[e], s = src[e];
    int old = atomicExch(&head[d], e);
    rec[e] = make_int2(s, old);
}

// ---------- fused: chain-walk mean-aggregate + W0 projection + leaky + Weq ----------
// One wave per 4 nodes (2 chains walked concurrently to keep memory in flight).
// Projection reads W0 from LDS (per-lane, 2-way bank = free) and the staged sums
// as LDS broadcasts; epilogue reduces h @ Weq via shfl and writes 2 floats/node.
__global__ __launch_bounds__(256) void agg_proj(const float* __restrict__ feat,
                                                const int* __restrict__ headC,
                                                const int2* __restrict__ recC,
                                                const int* __restrict__ headM,
                                                const int2* __restrict__ recM,
                                                const float* __restrict__ W0C,
                                                const float* __restrict__ b0C,
                                                const float* __restrict__ WqC,
                                                const float* __restrict__ W0M,
                                                const float* __restrict__ b0M,
                                                const float* __restrict__ WqM,
                                                float* __restrict__ pC,
                                                float* __restrict__ pM) {
    __shared__ float Ws[128 * 64];     // 32 KB
    __shared__ float sst[4][4][128];   // 8 KB: [wave][node-slot][channel]
    int tid = threadIdx.x;
    bool isM = blockIdx.x >= CBLK;
    const int* head; const int2* rec; const float* W0; const float* b0; const float* Wq;
    float* p; int base;
    if (!isM) { head = headC; rec = recC; W0 = W0C; b0 = b0C; Wq = WqC; p = pC;
                base = blockIdx.x * 16; }
    else      { head = headM; rec = recM; W0 = W0M; b0 = b0M; Wq = WqM; p = pM;
                base = (blockIdx.x - CBLK) * 16; }
    {   // cooperative W0 -> LDS (float4)
        const float4* W4 = (const float4*)W0;
        float4* Ws4 = (float4*)Ws;
        for (int i = tid; i < 2048; i += 256) Ws4[i] = W4[i];
    }
    int lane = tid & 63, wv = tid >> 6;
    const float* fp = feat + lane * 2;
    int cn[4];
    // walk chains pairwise: (0,1) then (2,3); chain heads are wave-uniform
#pragma unroll
    for (int pr = 0; pr < 2; pr++) {
        int n0 = base + wv * 4 + pr * 2;
        int e0 = head[n0];
        int e1 = head[n0 + 1];
        float ax0 = 0.f, ay0 = 0.f, ax1 = 0.f, ay1 = 0.f;
        int c0 = 0, c1 = 0;
        while (e0 >= 0 || e1 >= 0) {
            if (e0 >= 0) {
                int2 rc = rec[e0];
                const float2 v = *(const float2*)(fp + (size_t)rc.x * 128);
                ax0 += v.x; ay0 += v.y; c0++; e0 = rc.y;
            }
            if (e1 >= 0) {
                int2 rc = rec[e1];
                const float2 v = *(const float2*)(fp + (size_t)rc.x * 128);
                ax1 += v.x; ay1 += v.y; c1++; e1 = rc.y;
            }
        }
        *(float2*)&sst[wv][pr * 2 + 0][lane * 2] = make_float2(ax0, ay0);
        *(float2*)&sst[wv][pr * 2 + 1][lane * 2] = make_float2(ax1, ay1);
        cn[pr * 2 + 0] = c0;
        cn[pr * 2 + 1] = c1;
    }
    __syncthreads();   // orders W0 stores + sst stores before reads
    int col = lane;
    float a0 = 0.f, a1 = 0.f, a2 = 0.f, a3 = 0.f;
#pragma unroll 4
    for (int k = 0; k < 128; k += 4) {
        float w0 = Ws[(k + 0) * 64 + col];
        float w1 = Ws[(k + 1) * 64 + col];
        float w2 = Ws[(k + 2) * 64 + col];
        float w3 = Ws[(k + 3) * 64 + col];
        const float4 s0 = *(const float4*)&sst[wv][0][k];
        const float4 s1 = *(const float4*)&sst[wv][1][k];
        const float4 s2 = *(const float4*)&sst[wv][2][k];
        const float4 s3 = *(const float4*)&sst[wv][3][k];
        a0 += s0.x * w0 + s0.y * w1 + s0.z * w2 + s0.w * w3;
        a1 += s1.x * w0 + s1.y * w1 + s1.z * w2 + s1.w * w3;
        a2 += s2.x * w0 + s2.y * w1 + s2.z * w2 + s2.w * w3;
        a3 += s3.x * w0 + s3.y * w1 + s3.z * w2 + s3.w * w3;
    }
    float b0c = b0[col];
    float wq0 = Wq[col * 2 + 0], wq1 = Wq[col * 2 + 1];
    float acc[4] = {a0, a1, a2, a3};
#pragma unroll
    for (int j = 0; j < 4; j++) {
        float h = 0.0f;
        if (cn[j] > 0) {
            float v = acc[j] / (float)cn[j] + b0c;
            h = v > 0.0f ? v : 0.01f * v;
        }
        float p0 = h * wq0, p1 = h * wq1;
#pragma unroll
        for (int off = 32; off; off >>= 1) {
            p0 += __shfl_down(p0, off, 64);
            p1 += __shfl_down(p1, off, 64);
        }
        if (lane == 0) {
            int node = base + wv * 4 + j;
            p[(size_t)node * 2 + 0] = p0;
            p[(size_t)node * 2 + 1] = p1;
        }
    }
}

// ---------- layer 1: dual chain gather (interleaved) fused with final linear ----------
__global__ __launch_bounds__(256) void gather_final(const float* __restrict__ pC,
                                                    const int* __restrict__ headTC,
                                                    const int2* __restrict__ recTC,
                                                    const float* __restrict__ pM,
                                                    const int* __restrict__ headTM,
                                                    const int2* __restrict__ recTM,
                                                    const float* __restrict__ beq,
                                                    const float* __restrict__ bfv,
                                                    float* __restrict__ out) {
    int i = blockIdx.x * 256 + threadIdx.x;
    if (i >= NT) return;
    int e0 = headTC[i];
    int e1 = headTM[i];
    float c0a = 0.f, c0b = 0.f, c1a = 0.f, c1b = 0.f;
    int n0 = 0, n1 = 0;
    while (e0 >= 0 || e1 >= 0) {
        if (e0 >= 0) {
            int2 rc = recTC[e0];
            const float2 v = *(const float2*)(pC + (size_t)rc.x * 2);
            c0a += v.x; c0b += v.y; n0++; e0 = rc.y;
        }
        if (e1 >= 0) {
            int2 rc = recTM[e1];
            const float2 v = *(const float2*)(pM + (size_t)rc.x * 2);
            c1a += v.x; c1b += v.y; n1++; e1 = rc.y;
        }
    }
    float r0 = bfv[0], r1 = bfv[1];
    if (n0 > 0) {
        float inv = 1.0f / (float)n0;
        r0 += c0a * inv + beq[0];
        r1 += c0b * inv + beq[1];
    }
    if (n1 > 0) {
        float inv = 1.0f / (float)n1;
        r0 += c1a * inv + beq[2];
        r1 += c1b * inv + beq[3];
    }
    float2 o; o.x = r0; o.y = r1;
    *(float2*)(out + (size_t)i * 2) = o;
}

extern "C" void kernel_launch(void* const* d_in, const int* in_sizes, int n_in,
                              void* d_out, int out_size, void* d_ws, size_t ws_size,
                              hipStream_t stream) {
    const float* feat = (const float*)d_in[0];
    const int* src_c2t = (const int*)d_in[3];
    const int* dst_c2t = (const int*)d_in[4];
    const int* src_m2t = (const int*)d_in[5];
    const int* dst_m2t = (const int*)d_in[6];
    const int* src_t2c = (const int*)d_in[7];
    const int* dst_t2c = (const int*)d_in[8];
    const int* src_t2m = (const int*)d_in[9];
    const int* dst_t2m = (const int*)d_in[10];
    const float* W1_c2t = (const float*)d_in[13];
    const float* b1_c2t = (const float*)d_in[14];
    const float* W1_m2t = (const float*)d_in[17];
    const float* b1_m2t = (const float*)d_in[18];
    const float* W0_t2c = (const float*)d_in[19];
    const float* b0_t2c = (const float*)d_in[20];
    const float* W0_t2m = (const float*)d_in[23];
    const float* b0_t2m = (const float*)d_in[24];
    const float* Wf  = (const float*)d_in[27];
    const float* bfv = (const float*)d_in[28];

    char* ws = (char*)d_ws;
    // Footprint ~21.5 MB (SUM + cnt arrays eliminated).
    // four head arrays adjacent -> ONE 0xFF memset (init to -1)
    int*   headC   = (int*)(ws + 0);              // NC*4   = 400,000
    int*   headM   = (int*)(ws + 400000);         // NM*4   = 80,000
    int*   headTC  = (int*)(ws + 480000);         // NT*4   = 2,000,000
    int*   headTM  = (int*)(ws + 2480000);        // NT*4   = 2,000,000
    int2*  recC    = (int2*)(ws + 4480000);       // NE*8   = 4,000,000
    int2*  recM    = (int2*)(ws + 8480000);       // 4,000,000
    int2*  recTC   = (int2*)(ws + 12480000);      // 4,000,000
    int2*  recTM   = (int2*)(ws + 16480000);      // 4,000,000
    float* pC      = (float*)(ws + 20480000);     // NC*2*4 = 800,000
    float* pM      = (float*)(ws + 21280000);     // NM*2*4 = 160,000
    float* WeqC    = (float*)(ws + 21440000);     // 512
    float* WeqM    = (float*)(ws + 21440512);     // 512
    float* beq     = (float*)(ws + 21441024);     // 16 -> end ~21.44 MB

    // init all four head arrays to -1 in one call
    hipMemsetAsync(headC, 0xFF, 4480000, stream);

    weq_kernel<<<1, 256, 0, stream>>>(W1_c2t, b1_c2t, W1_m2t, b1_m2t, Wf, WeqC, WeqM, beq);

    // ---- build all four linked chains in one launch ----
    chain4<<<7813, 256, 0, stream>>>(src_t2c, dst_t2c, src_t2m, dst_t2m,
                                     src_c2t, dst_c2t, src_m2t, dst_m2t,
                                     headC, headM, headTC, headTM,
                                     recC, recM, recTC, recTM);

    // ---- layer 0 fused: walk + mean + W0 + leaky + Weq, clients & merchants ----
    agg_proj<<<CBLK + MBLK, 256, 0, stream>>>(feat, headC, recC, headM, recM,
                                              W0_t2c, b0_t2c, WeqC,
                                              W0_t2m, b0_t2m, WeqM,
                                              pC, pM);

    // ---- layer 1: dual-chain gather fused with final linear ----
    gather_final<<<1954, 256, 0, stream>>>(pC, headTC, recTC,
                                           pM, headTM, recTM,
                                           beq, bfv, (float*)d_out);
}